// Round 2
// baseline (127.848 us; speedup 1.0000x reference)
//
#include <hip/hip_runtime.h>

// DTW loss: sum |preds[b, path_i[b,p]] - targets[b, path_j[b,p]]|_1 / (B*S)
// B=256, S=8192, P=16383. preds/targets fp32 (B,S,2); path_* int32 (B,P).
// Ideal HBM traffic ~67 MB -> ~10.6 us floor at 6.3 TB/s.
// R0 post-mortem: latency-bound (Occ 23%, VALU 2%, HBM 19%). R1: 2048 blocks
// -> 8 blocks/CU = 32 waves/CU (VGPR=40 permits it), keep XCD-affinity swizzle.

#define BB 256
#define SS 8192
#define PP 16383
#define CH 2048   // pairs handled per block (8 blocks per batch)

__global__ __launch_bounds__(256) void dtw_loss_kernel(
    const float* __restrict__ preds,
    const float* __restrict__ targets,
    const int* __restrict__ path_i,
    const int* __restrict__ path_j,
    float* __restrict__ out)
{
    // XCD-affinity swizzle: consecutive blockIdx round-robin across 8 XCDs,
    // so invert: all 8 chunks of batch b land on XCD b%8 -> the batch's
    // 128 KB gather window is fetched into exactly one L2.
    const int xcd   = blockIdx.x & 7;          // 0..7
    const int slot  = blockIdx.x >> 3;         // 0..255
    const int batch = xcd + 8 * (slot >> 3);   // 0..255, batch%8 == xcd
    const int chunk = slot & 7;                // 0..7

    const float2* __restrict__ p2 = (const float2*)preds   + (size_t)batch * SS;
    const float2* __restrict__ t2 = (const float2*)targets + (size_t)batch * SS;
    const int*    __restrict__ pi = path_i + (size_t)batch * PP + chunk * CH;
    const int*    __restrict__ pj = path_j + (size_t)batch * PP + chunk * CH;
    const int n = min(PP - chunk * CH, CH);    // 2048, or 2047 for chunk 7

    // 4 accumulators: keep the VALU dependency chain off the critical path.
    float a0 = 0.f, a1 = 0.f, a2 = 0.f, a3 = 0.f;

    if (n == CH) {
        // Fully unrolled: 8 index-pair loads + 16 independent gathers per
        // thread that the compiler can batch ahead of the waitcnt.
        #pragma unroll
        for (int u = 0; u < CH / 256; ++u) {
            const int k = u * 256 + threadIdx.x;
            const int i = pi[k];
            const int j = pj[k];
            const float2 a = p2[i];
            const float2 b = t2[j];
            const float d = fabsf(a.x - b.x) + fabsf(a.y - b.y);
            if ((u & 3) == 0) a0 += d;
            else if ((u & 3) == 1) a1 += d;
            else if ((u & 3) == 2) a2 += d;
            else a3 += d;
        }
    } else {
        for (int k = threadIdx.x; k < n; k += 256) {
            const int i = pi[k];
            const int j = pj[k];
            const float2 a = p2[i];
            const float2 b = t2[j];
            a0 += fabsf(a.x - b.x) + fabsf(a.y - b.y);
        }
    }

    float acc = (a0 + a1) + (a2 + a3);

    // Wave (64-lane) shuffle reduction
    #pragma unroll
    for (int off = 32; off > 0; off >>= 1)
        acc += __shfl_down(acc, off, 64);

    __shared__ float wsum[4];
    const int lane = threadIdx.x & 63;
    const int wid  = threadIdx.x >> 6;
    if (lane == 0) wsum[wid] = acc;
    __syncthreads();
    if (threadIdx.x == 0) {
        const float s = wsum[0] + wsum[1] + wsum[2] + wsum[3];
        // scale 1/(B*S) = 2^-21, exact in fp32
        atomicAdd(out, s * (1.0f / ((float)BB * (float)SS)));
    }
}

extern "C" void kernel_launch(void* const* d_in, const int* in_sizes, int n_in,
                              void* d_out, int out_size, void* d_ws, size_t ws_size,
                              hipStream_t stream) {
    const float* preds   = (const float*)d_in[0];
    const float* targets = (const float*)d_in[1];
    const int*   path_i  = (const int*)d_in[2];
    const int*   path_j  = (const int*)d_in[3];
    float* out = (float*)d_out;

    // d_out is poisoned 0xAA before every launch; stream-ordered memset is
    // graph-capture legal (the harness itself uses hipMemsetAsync).
    hipMemsetAsync(out, 0, sizeof(float), stream);

    const int blocks = BB * 8;  // 2048 blocks, 8 per batch
    dtw_loss_kernel<<<blocks, 256, 0, stream>>>(preds, targets, path_i, path_j, out);
}